// Round 1
// baseline (1594.221 us; speedup 1.0000x reference)
//
#include <hip/hip_runtime.h>
#include <math.h>
#include <stdint.h>

// Problem constants
#define B_   256
#define T_   128
#define NIN_ 1024
#define H1_  512
#define E_   256
#define A_   16
#define MT_  (B_ * T_)   // 32768 rows, t-major: m = t*B_ + b

typedef unsigned short ushort_t;
typedef __attribute__((ext_vector_type(8))) short   short8;
typedef __attribute__((ext_vector_type(8))) __bf16  bf16x8;
typedef __attribute__((ext_vector_type(4))) float   f32x4;

union frag8 { short8 s; bf16x8 b; };

__device__ __forceinline__ ushort_t f2bf(float f) {
  union { float f; unsigned u; } v; v.f = f;
  unsigned r = (v.u + 0x7FFFu + ((v.u >> 16) & 1u)) >> 16;   // RNE
  return (ushort_t)r;
}

// ---------------- workspace layout (bytes) ----------------
// C0 fp32 [T*B][1024] = 128MB at 0 (written late; obs_b bf16 64MB overlays it early)
// chunks of C0 row: [0:256)=Penc(h_enc init) [256:512)=r_pre0 [512:768)=z_pre0 [768:1024)=hn0
static constexpr size_t OFF_C0    = 0;
static constexpr size_t OFF_OBSB  = 0;                      // bf16 [32768][1024], dead after G1
static constexpr size_t OFF_Y     = 134217728;              // fp32 [32768][512] (Y1,Y2)
static constexpr size_t OFF_YG    = 134217728;              // fp32 [32768][256] (after Y2 dead)
static constexpr size_t OFF_XG    = 167772160;              // bf16 [32768][256]
static constexpr size_t OFF_PENCB = 184549376;              // bf16 [32768][256] (after BN2)
static constexpr size_t OFF_XB    = 201326592;              // bf16 [32768][512] (X1,X2)
static constexpr size_t OFF_INN   = 201326592;              // fp32 [32768][256] (after XB dead)
static constexpr size_t OFF_AE    = 234881024;              // fp32 [32768][16]
static constexpr size_t OFF_W1T   = 236978176;              // bf16 [512][1024]
static constexpr size_t OFF_W2T   = 238026752;              // bf16 [512][512]
static constexpr size_t OFF_W3T   = 238551040;              // bf16 [256][512]
static constexpr size_t OFF_WIHT  = 239075328;              // bf16 [768][256]
static constexpr size_t OFF_WHHT  = 239468544;              // bf16 [768][256]
static constexpr size_t OFF_WCT   = 240123904;              // bf16 [1024][256]  (combined W^T)
static constexpr size_t OFF_BSUM  = 241172480;              // fp32 [768]
static constexpr size_t OFF_H0    = 241238016;              // bf16 [256][256]
static constexpr size_t OFF_H1    = 241369088;              // bf16 [256][256]

// ---------------- prologue kernels ----------------

// obs [B,T,NIN] fp32 -> obs_b bf16 t-major [t*B+b][NIN]
__global__ __launch_bounds__(256) void cast_obs_k(const float* __restrict__ obs,
                                                  ushort_t* __restrict__ out) {
  int row_in = blockIdx.x;              // b*T + t
  int b = row_in / T_, t = row_in - b * T_;
  const float4* s4 = (const float4*)(obs + (size_t)row_in * NIN_);
  float4 v = s4[threadIdx.x];
  ushort_t* d = out + (size_t)(t * B_ + b) * NIN_ + threadIdx.x * 4;
  d[0] = f2bf(v.x); d[1] = f2bf(v.y); d[2] = f2bf(v.z); d[3] = f2bf(v.w);
}

// generic fp32 [R,C] -> bf16 [C,R] transpose+cast
__global__ __launch_bounds__(256) void transpose_cast_k(const float* __restrict__ in,
                                                        ushort_t* __restrict__ out,
                                                        int R, int C) {
  __shared__ float tile[32][33];
  int c0 = blockIdx.x * 32, r0 = blockIdx.y * 32;
  int tx = threadIdx.x & 31, ty = threadIdx.x >> 5;   // ty 0..7
  for (int i = 0; i < 4; i++) {
    int r = r0 + ty * 4 + i;
    if (r < R && (c0 + tx) < C) tile[ty * 4 + i][tx] = in[(size_t)r * C + c0 + tx];
  }
  __syncthreads();
  for (int i = 0; i < 4; i++) {
    int c = c0 + ty * 4 + i, r = r0 + tx;
    if (c < C && r < R) out[(size_t)c * R + r] = f2bf(tile[tx][ty * 4 + i]);
  }
}

// Wct rows 0..255: (Whe_h)^T  : Wct[c][k] = Whe[k][c]
__global__ __launch_bounds__(256) void wct_a_k(const float* __restrict__ Whe,
                                               ushort_t* __restrict__ Wct) {
  int c = blockIdx.x, k = threadIdx.x;
  Wct[(size_t)c * 256 + k] = f2bf(Whe[(size_t)k * 256 + c]);
}

// Wct rows 256..1023: (Whe_h @ Whh)^T computed in fp32, one bf16 rounding
__global__ __launch_bounds__(256) void wct_b_k(const float* __restrict__ Whe,
                                               const float* __restrict__ Whh,
                                               ushort_t* __restrict__ Wct) {
  int c = blockIdx.x;   // 0..767 (gh column)
  int k = threadIdx.x;  // h feature
  float acc = 0.f;
  for (int j = 0; j < 256; j++)
    acc += Whe[(size_t)k * 256 + j] * Whh[(size_t)j * 768 + c];
  Wct[(size_t)(256 + c) * 256 + k] = f2bf(acc);
}

__global__ void bsum_k(const float* __restrict__ bih, const float* __restrict__ bhh,
                       float* __restrict__ bs) {
  int i = blockIdx.x * 256 + threadIdx.x;
  if (i < 768) bs[i] = bih[i] + bhh[i];
}

__global__ void zero_k(ushort_t* p, int n) {
  int i = blockIdx.x * 256 + threadIdx.x;
  if (i < n) p[i] = 0;
}

// AE[m=t*B+b][k2] = actions[b,t,:] @ Wae + bae   (fp32)
__global__ __launch_bounds__(256) void ae_k(const float* __restrict__ actions,
                                            const float* __restrict__ Wae,
                                            const float* __restrict__ bae,
                                            float* __restrict__ AE) {
  int idx = blockIdx.x * 256 + threadIdx.x;
  int m = idx >> 4, k2 = idx & 15;
  int t = m >> 8, b = m & 255;
  const float* arow = actions + ((size_t)b * T_ + t) * A_;
  float acc = bae[k2];
  for (int k = 0; k < 16; k++) acc += arow[k] * Wae[k * 16 + k2];
  AE[(size_t)m * 16 + k2] = acc;
}

// Penc[t][b][j] = bhe[j] + (t>0 ? AE[t-1,b,:] @ Whe[256:272,:] : 0)
// writes fp32 into C0 cols [0:256) and bf16 copy to Pencb
__global__ __launch_bounds__(256) void penc_k(const float* __restrict__ AE,
                                              const float* __restrict__ Whe,
                                              const float* __restrict__ bhe,
                                              float* __restrict__ C0,
                                              ushort_t* __restrict__ Pencb) {
  int m = blockIdx.x;          // t*B + b
  int j = threadIdx.x;         // 0..255
  __shared__ float a[16];
  if (threadIdx.x < 16)
    a[threadIdx.x] = (m >= B_) ? AE[(size_t)(m - B_) * 16 + threadIdx.x] : 0.f;
  __syncthreads();
  float acc = bhe[j];
  if (m >= B_) {
    for (int k = 0; k < 16; k++) acc += a[k] * Whe[(size_t)(256 + k) * 256 + j];
  }
  C0[(size_t)m * 1024 + j] = acc;
  Pencb[(size_t)m * 256 + j] = f2bf(acc);
}

// per-t BatchNorm (training, biased var) + ELU, fp32 in -> bf16 out
__global__ __launch_bounds__(512) void bn_elu_k(const float* __restrict__ Y,
                                                const float* __restrict__ g,
                                                const float* __restrict__ be,
                                                ushort_t* __restrict__ Xb) {
  int t = blockIdx.x, f = threadIdx.x;   // 512 features
  const float* base = Y + (size_t)t * B_ * H1_;
  float s = 0.f, ss = 0.f;
  for (int b = 0; b < B_; b++) {
    float v = base[(size_t)b * H1_ + f];
    s += v; ss += v * v;
  }
  float mu  = s * (1.f / B_);
  float var = ss * (1.f / B_) - mu * mu;
  float inv = 1.f / sqrtf(var + 1e-5f);
  float sc = g[f] * inv, sh = be[f] - mu * sc;
  ushort_t* ob = Xb + (size_t)t * B_ * H1_;
  for (int b = 0; b < B_; b++) {
    float v = base[(size_t)b * H1_ + f] * sc + sh;
    float e = v > 0.f ? v : (expf(v) - 1.f);
    ob[(size_t)b * H1_ + f] = f2bf(e);
  }
}

__global__ __launch_bounds__(256) void cast_k(const float* __restrict__ in,
                                              ushort_t* __restrict__ out, long n) {
  long i = (long)blockIdx.x * 256 + threadIdx.x;
  if (i < n) out[i] = f2bf(in[i]);
}

// ---------------- bf16 MFMA GEMM: C[m,n] (+)= A[m,:] . Bt[n,:] + bias[n] ----------------
// A: bf16 [M,lda], Bt: bf16 [N,ldb] (B transposed), C: fp32 (ldc), 64x64 tile, BK=32.
// grid = (M/64, N/64), 256 threads (4 waves in 2x2).
__global__ __launch_bounds__(256) void gemm_bt_k(const ushort_t* __restrict__ A, int lda,
                                                 const ushort_t* __restrict__ Bt, int ldb,
                                                 float* __restrict__ C, int ldc,
                                                 const float* __restrict__ bias,
                                                 int K, int accum) {
  __shared__ __align__(16) ushort_t As[64][40];  // +8 pad: 2-way banks (free)
  __shared__ __align__(16) ushort_t Bs[64][40];
  int tid = threadIdx.x;
  int wave = tid >> 6, lane = tid & 63;
  int q = lane >> 4, l15 = lane & 15;
  int wr = wave >> 1, wc = wave & 1;
  int m0 = blockIdx.x * 64, n0 = blockIdx.y * 64;
  f32x4 acc[2][2] = {};
  int r = tid >> 2, seg = tid & 3;
  const ushort_t* aSrc = A + (size_t)(m0 + r) * lda + seg * 8;
  const ushort_t* bSrc = Bt + (size_t)(n0 + r) * ldb + seg * 8;
  for (int k0 = 0; k0 < K; k0 += 32) {
    *(short8*)&As[r][seg * 8] = *(const short8*)(aSrc + k0);
    *(short8*)&Bs[r][seg * 8] = *(const short8*)(bSrc + k0);
    __syncthreads();
    frag8 a0, a1, b0, b1;
    a0.s = *(const short8*)&As[wr * 32 + l15][q * 8];
    a1.s = *(const short8*)&As[wr * 32 + 16 + l15][q * 8];
    b0.s = *(const short8*)&Bs[wc * 32 + l15][q * 8];
    b1.s = *(const short8*)&Bs[wc * 32 + 16 + l15][q * 8];
    acc[0][0] = __builtin_amdgcn_mfma_f32_16x16x32_bf16(a0.b, b0.b, acc[0][0], 0, 0, 0);
    acc[0][1] = __builtin_amdgcn_mfma_f32_16x16x32_bf16(a0.b, b1.b, acc[0][1], 0, 0, 0);
    acc[1][0] = __builtin_amdgcn_mfma_f32_16x16x32_bf16(a1.b, b0.b, acc[1][0], 0, 0, 0);
    acc[1][1] = __builtin_amdgcn_mfma_f32_16x16x32_bf16(a1.b, b1.b, acc[1][1], 0, 0, 0);
    __syncthreads();
  }
  for (int at = 0; at < 2; at++)
    for (int bt = 0; bt < 2; bt++) {
      int mb = m0 + wr * 32 + at * 16 + q * 4;       // C/D: row = quad*4+i
      int n  = n0 + wc * 32 + bt * 16 + l15;         //      col = lane&15
      float bv = bias ? bias[n] : 0.f;
      for (int i = 0; i < 4; i++) {
        size_t idx = (size_t)(mb + i) * ldc + n;
        float v = acc[at][bt][i] + bv;
        if (accum) v += C[idx];
        C[idx] = v;
      }
    }
}

// ---------------- fused GRU step ----------------
// OUT[256,1024] = h @ Wcomb + C0[t]; chunks [h_enc|r|z|hn]; gates + h update in-register.
// grid (4 row-blocks of 64, 16 col-groups of 16), 256 thr (4 waves = 4 row-tiles of 16).
__global__ __launch_bounds__(256) void gru_step_k(const ushort_t* __restrict__ hin,
                                                  const ushort_t* __restrict__ Wct,
                                                  const float* __restrict__ C0t,
                                                  const float* __restrict__ INNt,
                                                  ushort_t* __restrict__ hout,
                                                  float* __restrict__ outF) {
  __shared__ __align__(16) ushort_t As[64][264];  // 64 rows x 256 k (+8 pad)
  int tid = threadIdx.x;
  int wave = tid >> 6, lane = tid & 63;
  int q = lane >> 4, l15 = lane & 15;
  int rb = blockIdx.x, cg = blockIdx.y;
  {
    int r = tid >> 2, s0 = tid & 3;
    const ushort_t* src = hin + (size_t)(rb * 64 + r) * 256;
    for (int i = 0; i < 8; i++) {
      int s = s0 + i * 4;
      *(short8*)&As[r][s * 8] = *(const short8*)(src + s * 8);
    }
  }
  __syncthreads();
  f32x4 acc[4] = {};
  const ushort_t* wbase = Wct + (size_t)(cg * 16 + l15) * 256 + q * 8;
  for (int kc = 0; kc < 8; kc++) {
    frag8 a; a.s = *(const short8*)&As[wave * 16 + l15][kc * 32 + q * 8];
#pragma unroll
    for (int ch = 0; ch < 4; ch++) {
      frag8 b; b.s = *(const short8*)(wbase + (size_t)ch * 65536 + kc * 32);
      acc[ch] = __builtin_amdgcn_mfma_f32_16x16x32_bf16(a.b, b.b, acc[ch], 0, 0, 0);
    }
  }
  int col = cg * 16 + l15;
#pragma unroll
  for (int i = 0; i < 4; i++) {
    int row = rb * 64 + wave * 16 + q * 4 + i;     // batch index b
    size_t o = (size_t)row * 1024 + col;
    float henc = acc[0][i] + C0t[o];
    float rp   = acc[1][i] + C0t[o + 256];
    float zp   = acc[2][i] + C0t[o + 512];
    float hn   = acc[3][i] + C0t[o + 768];
    float rg = 1.f / (1.f + expf(-rp));
    float zg = 1.f / (1.f + expf(-zp));
    float inn = INNt[(size_t)row * 256 + col];
    float ng = tanhf(inn + rg * hn);
    float hv = (1.f - zg) * ng + zg * henc;
    hout[(size_t)row * 256 + col] = f2bf(hv);
    outF[(size_t)row * 256 + col] = hv;
  }
}

// ---------------- launch ----------------
extern "C" void kernel_launch(void* const* d_in, const int* in_sizes, int n_in,
                              void* d_out, int out_size, void* d_ws, size_t ws_size,
                              hipStream_t stream) {
  const float* obs     = (const float*)d_in[0];
  const float* actions = (const float*)d_in[1];
  const float* W1  = (const float*)d_in[2];
  const float* b1  = (const float*)d_in[3];
  const float* g1  = (const float*)d_in[4];
  const float* be1 = (const float*)d_in[5];
  const float* W2  = (const float*)d_in[6];
  const float* b2  = (const float*)d_in[7];
  const float* g2  = (const float*)d_in[8];
  const float* be2 = (const float*)d_in[9];
  const float* W3  = (const float*)d_in[10];
  const float* b3  = (const float*)d_in[11];
  const float* Wih = (const float*)d_in[12];
  const float* bih = (const float*)d_in[13];
  const float* Whh = (const float*)d_in[14];
  const float* bhh = (const float*)d_in[15];
  const float* Whe = (const float*)d_in[16];
  const float* bhe = (const float*)d_in[17];
  const float* Wae = (const float*)d_in[18];
  const float* bae = (const float*)d_in[19];

  char* ws = (char*)d_ws;
  float*    C0    = (float*)(ws + OFF_C0);
  ushort_t* obsb  = (ushort_t*)(ws + OFF_OBSB);
  float*    Y     = (float*)(ws + OFF_Y);
  float*    Yg    = (float*)(ws + OFF_YG);
  ushort_t* XG    = (ushort_t*)(ws + OFF_XG);
  ushort_t* Pencb = (ushort_t*)(ws + OFF_PENCB);
  ushort_t* Xb    = (ushort_t*)(ws + OFF_XB);
  float*    INN   = (float*)(ws + OFF_INN);
  float*    AE    = (float*)(ws + OFF_AE);
  ushort_t* W1t   = (ushort_t*)(ws + OFF_W1T);
  ushort_t* W2t   = (ushort_t*)(ws + OFF_W2T);
  ushort_t* W3t   = (ushort_t*)(ws + OFF_W3T);
  ushort_t* Wiht  = (ushort_t*)(ws + OFF_WIHT);
  ushort_t* Whht  = (ushort_t*)(ws + OFF_WHHT);
  ushort_t* Wct   = (ushort_t*)(ws + OFF_WCT);
  float*    bsum  = (float*)(ws + OFF_BSUM);
  ushort_t* h0    = (ushort_t*)(ws + OFF_H0);
  ushort_t* h1    = (ushort_t*)(ws + OFF_H1);
  float*    outF  = (float*)d_out;

  // prologue: casts / transposes / small precomputes
  cast_obs_k<<<MT_, 256, 0, stream>>>(obs, obsb);
  transpose_cast_k<<<dim3(16, 32), 256, 0, stream>>>(W1, W1t, 1024, 512);
  transpose_cast_k<<<dim3(16, 16), 256, 0, stream>>>(W2, W2t, 512, 512);
  transpose_cast_k<<<dim3(8, 16),  256, 0, stream>>>(W3, W3t, 512, 256);
  transpose_cast_k<<<dim3(24, 8),  256, 0, stream>>>(Wih, Wiht, 256, 768);
  transpose_cast_k<<<dim3(24, 8),  256, 0, stream>>>(Whh, Whht, 256, 768);
  wct_a_k<<<256, 256, 0, stream>>>(Whe, Wct);
  wct_b_k<<<768, 256, 0, stream>>>(Whe, Whh, Wct);
  bsum_k<<<3, 256, 0, stream>>>(bih, bhh, bsum);
  zero_k<<<256, 256, 0, stream>>>(h0, 65536);
  ae_k<<<MT_ * 16 / 256, 256, 0, stream>>>(actions, Wae, bae, AE);

  // MLP (parallel over all T*B rows, t-major)
  gemm_bt_k<<<dim3(512, 8), 256, 0, stream>>>(obsb, 1024, W1t, 1024, Y, 512, b1, 1024, 0);
  bn_elu_k<<<T_, 512, 0, stream>>>(Y, g1, be1, Xb);
  gemm_bt_k<<<dim3(512, 8), 256, 0, stream>>>(Xb, 512, W2t, 512, Y, 512, b2, 512, 0);
  bn_elu_k<<<T_, 512, 0, stream>>>(Y, g2, be2, Xb);
  gemm_bt_k<<<dim3(512, 4), 256, 0, stream>>>(Xb, 512, W3t, 512, Yg, 256, b3, 512, 0);
  cast_k<<<MT_ * 256 / 256, 256, 0, stream>>>(Yg, XG, (long)MT_ * 256);

  // per-step constants: Penc -> C0[:,0:256); r/z pre -> C0[:,256:768); hn0 -> C0[:,768:1024); INN
  penc_k<<<MT_, 256, 0, stream>>>(AE, Whe, bhe, C0, Pencb);
  gemm_bt_k<<<dim3(512, 8), 256, 0, stream>>>(XG, 256, Wiht, 256, C0 + 256, 1024, bsum, 256, 0);
  gemm_bt_k<<<dim3(512, 8), 256, 0, stream>>>(Pencb, 256, Whht, 256, C0 + 256, 1024, nullptr, 256, 1);
  gemm_bt_k<<<dim3(512, 4), 256, 0, stream>>>(Pencb, 256, Whht + 512 * 256, 256, C0 + 768, 1024, bhh + 512, 256, 0);
  gemm_bt_k<<<dim3(512, 4), 256, 0, stream>>>(XG, 256, Wiht + 512 * 256, 256, INN, 256, bih + 512, 256, 0);

  // sequential recurrence: one fused kernel per step, double-buffered h
  for (int t = 0; t < T_; t++) {
    const ushort_t* hi = (t & 1) ? h1 : h0;
    ushort_t*       ho = (t & 1) ? h0 : h1;
    gru_step_k<<<dim3(4, 16), 256, 0, stream>>>(
        hi, Wct, C0 + (size_t)t * B_ * 1024, INN + (size_t)t * B_ * 256, ho, outF);
  }
}